// Round 14
// baseline (40.542 us; speedup 1.0000x reference)
//
#include <hip/hip_runtime.h>
#include <hip/hip_bf16.h>
#include <math.h>

#define B_ 512
#define C_ 100000
#define D_ 128
#define SC 64                          // proxy cols per step
#define NSTEP ((C_ + SC - 1) / SC)     // 1563 steps
#define NPAD (NSTEP * SC - C_)         // 32 zero-padded cols
#define GRID_MAIN 256                  // persistent, 1 block/CU
#define LOG2E 1.4426950408889634f
#define K2S (2.0f * LOG2E)             // score_log2 = dot*K2S + K18S
#define K18S (-18.0f * LOG2E)

typedef __attribute__((ext_vector_type(8))) short short8;  // 8 bf16 (MFMA A/B frag)
typedef __attribute__((ext_vector_type(4))) float f32x4;   // MFMA C/D frag

__device__ __forceinline__ float b2f(unsigned short u) {
  union { float f; unsigned int i; } v; v.i = ((unsigned int)u) << 16; return v.f;
}

#if defined(__has_builtin)
#if __has_builtin(__builtin_amdgcn_exp2f)
#define EXP2F(x) __builtin_amdgcn_exp2f(x)
#endif
#endif
#ifndef EXP2F
#define EXP2F(x) __expf(0.69314718055994531f * (x))
#endif

// async global -> LDS, 16 B per lane; LDS dest = wave-uniform base, HW adds lane*16
__device__ __forceinline__ void gll16(const void* g, void* l) {
  __builtin_amdgcn_global_load_lds(
      (const __attribute__((address_space(1))) void*)g,
      (__attribute__((address_space(3))) void*)l, 16, 0, 0);
}

// --- fused persistent main ----------------------------------------------------
// 256 blocks x 512 thr (8 waves); block b owns steps st = b, b+256, ...
// 3-deep pipeline, counted vmcnt (T3/T4): per iter {STAGE(s+2) ; vmcnt(4) ;
// barrier ; CVT(s+1) + COMPUTE(s) ; barrier}. part[4][4] accumulates across all
// steps; one pt write per block. A-frags self-normalized from raw batch.
__global__ __launch_bounds__(512, 2) void pnca_main_kernel(
    const float* __restrict__ praw, const float* __restrict__ batch,
    float* __restrict__ pt)
{
  __shared__ __align__(16) float         fbuf[2][SC * D_];       // 2 x 32 KB f32
  __shared__ __align__(16) unsigned char bbuf[2][SC * D_ * 2];   // 2 x 16 KB bf16 (swizzled)

  const int tid  = threadIdx.x;
  const int lane = tid & 63;
  const int w    = tid >> 6;
  const int ll   = lane & 15;
  const int lq   = lane >> 4;
  const int st0  = blockIdx.x;

  // A fragments: wave w owns batch rows w*64..w*64+63; load raw f32 (L2-hot),
  // normalize to norm 3 in-register, pack bf16. Row = m*16+ll (lq-independent).
  short8 a[4][4];
#pragma unroll
  for (int m = 0; m < 4; ++m) {
    float4 t0[4], t1[4];
    float ssm = 0.f;
#pragma unroll
    for (int ks = 0; ks < 4; ++ks) {
      const float* rp = batch + (size_t)(w * 64 + m * 16 + ll) * D_ + ks * 32 + lq * 8;
      t0[ks] = *(const float4*)rp;
      t1[ks] = *(const float4*)(rp + 4);
      ssm += t0[ks].x * t0[ks].x + t0[ks].y * t0[ks].y + t0[ks].z * t0[ks].z + t0[ks].w * t0[ks].w
           + t1[ks].x * t1[ks].x + t1[ks].y * t1[ks].y + t1[ks].z * t1[ks].z + t1[ks].w * t1[ks].w;
    }
    ssm += __shfl_xor(ssm, 16);
    ssm += __shfl_xor(ssm, 32);
    float sc = 3.f / fmaxf(sqrtf(ssm), 1e-12f);
#pragma unroll
    for (int ks = 0; ks < 4; ++ks) {
      union { short8 s8; __hip_bfloat162 h[4]; } u;
      u.h[0] = __float22bfloat162_rn(make_float2(t0[ks].x * sc, t0[ks].y * sc));
      u.h[1] = __float22bfloat162_rn(make_float2(t0[ks].z * sc, t0[ks].w * sc));
      u.h[2] = __float22bfloat162_rn(make_float2(t1[ks].x * sc, t1[ks].y * sc));
      u.h[3] = __float22bfloat162_rn(make_float2(t1[ks].z * sc, t1[ks].w * sc));
      a[m][ks] = u.s8;
    }
  }
  asm volatile("s_waitcnt vmcnt(0)" ::: "memory");   // A-loads retired: vmcnt tracks gll16 only

  float part[4][4];
#pragma unroll
  for (int m = 0; m < 4; ++m)
#pragma unroll
    for (int r = 0; r < 4; ++r) part[m][r] = 0.f;

  // stage step st's 64 cols x 512B raw f32 into fbuf[pp] (linear, 4 gll16/thread)
  auto STAGE = [&](int st, int pp) {
    const unsigned char* gb = (const unsigned char*)praw;
#pragma unroll
    for (int k = 0; k < 4; ++k) {
      int slot = k * 512 + tid;                 // 16B unit index within the tile
      int gr   = st * SC + (slot >> 5);         // proxy row
      if (gr >= C_) gr = C_ - 1;
      gll16(gb + ((size_t)gr * 32 + (slot & 31)) * 16,
            (unsigned char*)fbuf[pp] + (size_t)(k * 512 + w * 64) * 16);
    }
  };

  // cooperative convert: 8 threads per col; norm folded into bf16; swizzled B
  auto CVT = [&](int st, int pp) {
    const int c = tid >> 3, j = tid & 7;
    const float* Fb = fbuf[pp] + (size_t)c * D_;
    float x[16]; float ss = 0.f;
#pragma unroll
    for (int i = 0; i < 4; ++i) {
      float4 v = *(const float4*)(Fb + (j + 8 * i) * 4);
      x[4*i+0] = v.x; x[4*i+1] = v.y; x[4*i+2] = v.z; x[4*i+3] = v.w;
      ss += v.x * v.x + v.y * v.y + v.z * v.z + v.w * v.w;
    }
    ss += __shfl_xor(ss, 1);
    ss += __shfl_xor(ss, 2);
    ss += __shfl_xor(ss, 4);
    float sc = (st * SC + c < C_) ? 3.0f * __frsqrt_rn(fmaxf(ss, 1e-24f)) : 0.0f;
    unsigned char* Bb = bbuf[pp];
#pragma unroll
    for (int i = 0; i < 4; ++i) {
      union { unsigned long long q; __hip_bfloat162 h[2]; } u2;
      u2.h[0] = __float22bfloat162_rn(make_float2(x[4*i]   * sc, x[4*i+1] * sc));
      u2.h[1] = __float22bfloat162_rn(make_float2(x[4*i+2] * sc, x[4*i+3] * sc));
      int lu = (j >> 1) + 4 * i;                // logical 16B unit (dims 4j+32i..)
      int pu = lu ^ (c & 7);                    // XOR swizzle
      *(unsigned long long*)(Bb + ((size_t)c * 16 + pu) * 16 + (j & 1) * 8) = u2.q;
    }
  };

  auto COMPUTE = [&](int pp) {
    const unsigned char* Bb = bbuf[pp];
#pragma unroll
    for (int g = 0; g < 4; ++g) {
      const int cg = g * 16 + ll;
      short8 bfr[4];
#pragma unroll
      for (int ks = 0; ks < 4; ++ks)
        bfr[ks] = *(const short8*)(Bb + (size_t)(cg * 16 + ((ks * 4 + lq) ^ (cg & 7))) * 16);
      f32x4 acc[4];
#pragma unroll
      for (int m = 0; m < 4; ++m) acc[m] = (f32x4){0.f, 0.f, 0.f, 0.f};
#pragma unroll
      for (int ks = 0; ks < 4; ++ks)
#pragma unroll
        for (int m = 0; m < 4; ++m)
          acc[m] = __builtin_amdgcn_mfma_f32_16x16x32_bf16(a[m][ks], bfr[ks], acc[m], 0, 0, 0);
#pragma unroll
      for (int m = 0; m < 4; ++m)
#pragma unroll
        for (int r = 0; r < 4; ++r)
          part[m][r] += EXP2F(fmaf(acc[m][r], K2S, K18S));
    }
  };

  // prologue: two steps in flight, convert the first
  STAGE(st0, 0);
  STAGE(st0 + GRID_MAIN, 1);                 // st0+256 < 1563 for all blocks
  asm volatile("s_waitcnt vmcnt(4)" ::: "memory");   // F0 done; F1 in flight
  __builtin_amdgcn_s_barrier();
  __builtin_amdgcn_sched_barrier(0);
  CVT(st0, 0);
  __builtin_amdgcn_s_barrier();

  int cur = 0;
  for (int st = st0; st < NSTEP; st += GRID_MAIN) {
    const int s1 = st + GRID_MAIN;
    const int s2 = st + 2 * GRID_MAIN;
    const bool h1 = (s1 < NSTEP);
    const bool h2 = (s2 < NSTEP);
    if (h2) STAGE(s2, cur);                  // F[cur] already converted -> free
    if (h1) {
      if (h2) asm volatile("s_waitcnt vmcnt(4)" ::: "memory");  // F[cur^1] done
      else    asm volatile("s_waitcnt vmcnt(0)" ::: "memory");
    }
    __builtin_amdgcn_s_barrier();            // staged F visible block-wide
    __builtin_amdgcn_sched_barrier(0);
    if (h1) CVT(s1, cur ^ 1);                // convert next (VALU/LDS)
    COMPUTE(cur);                            // MFMA+exp current (independent)
    __builtin_amdgcn_s_barrier();            // B[cur^1] ready for next iter
    cur ^= 1;
  }

  // epilogue: 16-lane reduce of per-lane partial sums, one write per row
#pragma unroll
  for (int m = 0; m < 4; ++m)
#pragma unroll
    for (int r = 0; r < 4; ++r) {
      float v = part[m][r];
      v += __shfl_xor(v, 1);
      v += __shfl_xor(v, 2);
      v += __shfl_xor(v, 4);
      v += __shfl_xor(v, 8);
      if (ll == 0)
        pt[(size_t)blockIdx.x * B_ + w * 64 + m * 16 + lq * 4 + r] = v;
    }
}

// --- kernel 2: per-row combine + positive distance + loss ---------------------
__global__ __launch_bounds__(256) void finalize_rows_kernel(
    const float* __restrict__ praw, const float* __restrict__ batch,
    const int* __restrict__ labels, const float* __restrict__ pt,
    float* __restrict__ lossb)
{
  int lane = threadIdx.x & 63, wv = threadIdx.x >> 6;
  int row = blockIdx.x * 4 + wv;             // grid=128 -> 512 rows
  int lab = labels[row];
  float2 pv = *(const float2*)(praw + (size_t)lab * D_ + lane * 2);
  float2 xv = *(const float2*)(batch + (size_t)row * D_ + lane * 2);
  float ssp = pv.x * pv.x + pv.y * pv.y;
  float ssx = xv.x * xv.x + xv.y * xv.y;
  float dp  = xv.x * pv.x + xv.y * pv.y;
#pragma unroll
  for (int off = 32; off; off >>= 1) {
    ssp += __shfl_xor(ssp, off);
    ssx += __shfl_xor(ssx, off);
    dp  += __shfl_xor(dp, off);
  }
  // pd = 18 - 2*(3/||x||)*(3/||p||)*dot  (f.normalize eps semantics)
  float pd = 18.f - 18.f * dp / (fmaxf(sqrtf(ssx), 1e-12f) * fmaxf(sqrtf(ssp), 1e-12f));
  float s = 0.f;
#pragma unroll
  for (int gg = 0; gg < GRID_MAIN / 64; ++gg)
    s += pt[(size_t)(gg * 64 + lane) * B_ + row];
#pragma unroll
  for (int off = 32; off; off >>= 1) s += __shfl_xor(s, off);
  if (lane == 0) {
    const float tail = (float)NPAD * EXP2F(K18S);   // zero-padded cols' exact sum
    lossb[row] = pd + logf(s - __expf(-pd) - tail);
  }
}

// --- kernel 3: mean over 512 rows ---------------------------------------------
__global__ __launch_bounds__(512) void reduce_mean_kernel(
    const float* __restrict__ lossb, float* __restrict__ out)
{
  int t = threadIdx.x;
  float v = lossb[t];
#pragma unroll
  for (int off = 1; off < 64; off <<= 1) v += __shfl_xor(v, off);
  __shared__ float red[8];
  if ((t & 63) == 0) red[t >> 6] = v;
  __syncthreads();
  if (t == 0) {
    float tot = 0.f;
    for (int i = 0; i < 8; ++i) tot += red[i];
    out[0] = tot / (float)B_;
  }
}

extern "C" void kernel_launch(void* const* d_in, const int* in_sizes, int n_in,
                              void* d_out, int out_size, void* d_ws, size_t ws_size,
                              hipStream_t stream)
{
  const float* batch   = (const float*)d_in[0];
  const int*   labels  = (const int*)d_in[1];
  const float* proxies = (const float*)d_in[2];
  float* out = (float*)d_out;

  unsigned char* ws = (unsigned char*)d_ws;
  float* pt    = (float*)ws;                                   // 256*512*4 = 512 KB
  float* lossb = (float*)(ws + (size_t)GRID_MAIN * B_ * 4);    // 2 KB

  pnca_main_kernel<<<GRID_MAIN, 512, 0, stream>>>(proxies, batch, pt);
  finalize_rows_kernel<<<B_ / 4, 256, 0, stream>>>(proxies, batch, labels, pt, lossb);
  reduce_mean_kernel<<<1, 512, 0, stream>>>(lossb, out);
}